// Round 4
// baseline (483.159 us; speedup 1.0000x reference)
//
#include <hip/hip_runtime.h>

typedef _Float16 f16;
typedef _Float16 f16x4 __attribute__((ext_vector_type(4)));
typedef _Float16 f16x8 __attribute__((ext_vector_type(8)));
typedef float f32x4 __attribute__((ext_vector_type(4)));

#define DM 2048
#define NT 4096
#define SEQ 2048
#define HD 128
#define NBH 32
// 1/sqrt(128) * log2(e): scores come out in log2 domain -> exp2 is one v_exp_f32
#define QSCALE (0.08838834764831845f * 1.4426950408889634f)

__device__ __forceinline__ void gload16(const f16* g, f16* l) {
  __builtin_amdgcn_global_load_lds(
      (const __attribute__((address_space(1))) void*)g,
      (__attribute__((address_space(3))) void*)l, 16, 0, 0);
}

__global__ __launch_bounds__(256) void cvt_f32_f16(const float* __restrict__ src,
                                                   f16* __restrict__ dst, int n4) {
  int i = blockIdx.x * 256 + threadIdx.x;
  int st = gridDim.x * 256;
  for (; i < n4; i += st) {
    float4 v = ((const float4*)src)[i];
    f16x4 h = {(f16)v.x, (f16)v.y, (f16)v.z, (f16)v.w};
    ((f16x4*)dst)[i] = h;
  }
}

// concatenated weight convert: dst[0..1M) <- s0, [1M..2M) <- s1, [2M..3M) <- s2
// (each region is 2^20 f32x4 elements = 2048x2048 floats)
__global__ __launch_bounds__(256) void cvt3_f32_f16(const float* __restrict__ s0,
                                                    const float* __restrict__ s1,
                                                    const float* __restrict__ s2,
                                                    f16* __restrict__ dst) {
  int i = blockIdx.x * 256 + threadIdx.x;
  int st = gridDim.x * 256;
  for (; i < 3 * 1048576; i += st) {
    const int r = i >> 20, j = i & 1048575;
    const float* s = (r == 0) ? s0 : ((r == 1) ? s1 : s2);
    float4 v = ((const float4*)s)[j];
    f16x4 h = {(f16)v.x, (f16)v.y, (f16)v.z, (f16)v.w};
    ((f16x4*)dst)[i] = h;
  }
}

// C = A(4096x2048) * B^T; B row-major [N][2048]. 128x128 tile, BK=32,
// double-buffered LDS with ONE barrier per K-step (T3-minimum 2-phase).
// MODE 0: O-projection, f32 out [row][2048] + bo
// MODE 3: fused QKV (N=6144): region = col>>11 -> Q (bias+scale, [b,h,s,d]),
//         K ([b,h,s,d]), V (bias, transposed [b,h,d,s])
template <int MODE>
__global__ __launch_bounds__(256, 2) void gemm_bt(const f16* __restrict__ A,
                                                  const f16* __restrict__ B,
                                                  const float* __restrict__ bq,
                                                  const float* __restrict__ bv,
                                                  float* __restrict__ outF,
                                                  f16* __restrict__ outQ,
                                                  f16* __restrict__ outK,
                                                  f16* __restrict__ outV) {
  __shared__ __align__(16) f16 lA[2][128 * 32];
  __shared__ __align__(16) f16 lB[2][128 * 32];
  const int tid = threadIdx.x;
  const int w = tid >> 6, l = tid & 63;
  const int wr = w >> 1, wc = w & 1;
  const int row0 = blockIdx.y * 128, col0 = blockIdx.x * 128;

  f32x4 acc[4][4] = {};

  const int srow = w * 32 + (l >> 2);  // staging row (first 16); +16 for second
  const int sk = (l & 3) * 8;
  const f16* gA = A + (size_t)(row0 + srow) * DM + sk;
  const f16* gB = B + (size_t)(col0 + srow) * DM + sk;

  // prologue: stage K-step 0 into buffer 0
  {
    f16* sA = &lA[0][w * 1024];
    f16* sB = &lB[0][w * 1024];
    gload16(gA, sA);
    gload16(gA + 16 * DM, sA + 512);
    gload16(gB, sB);
    gload16(gB + 16 * DM, sB + 512);
  }

  int cur = 0;
  for (int k0 = 0; k0 < DM; k0 += 32) {
    __syncthreads();  // drains vmcnt(0): buffer `cur` ready; prev compute done
    if (k0 + 32 < DM) {
      f16* sA = &lA[cur ^ 1][w * 1024];
      f16* sB = &lB[cur ^ 1][w * 1024];
      gload16(gA + k0 + 32, sA);
      gload16(gA + k0 + 32 + 16 * DM, sA + 512);
      gload16(gB + k0 + 32, sB);
      gload16(gB + k0 + 32 + 16 * DM, sB + 512);
    }
    f16x8 af[4], bf[4];
#pragma unroll
    for (int i = 0; i < 4; i++)
      af[i] = *(const f16x8*)&lA[cur][(wr * 64 + i * 16 + (l & 15)) * 32 + (l >> 4) * 8];
#pragma unroll
    for (int i = 0; i < 4; i++)
      bf[i] = *(const f16x8*)&lB[cur][(wc * 64 + i * 16 + (l & 15)) * 32 + (l >> 4) * 8];
#pragma unroll
    for (int mi = 0; mi < 4; mi++)
#pragma unroll
      for (int ni = 0; ni < 4; ni++)
        acc[mi][ni] = __builtin_amdgcn_mfma_f32_16x16x32_f16(af[mi], bf[ni], acc[mi][ni], 0, 0, 0);
    cur ^= 1;
  }

  const int r0 = row0 + wr * 64 + (l >> 4) * 4;
  const int c0 = col0 + wc * 64 + (l & 15);
  if constexpr (MODE == 0) {
#pragma unroll
    for (int mi = 0; mi < 4; mi++) {
#pragma unroll
      for (int ni = 0; ni < 4; ni++) {
        const int col = c0 + ni * 16;
        const float bi = bq[col];
#pragma unroll
        for (int j = 0; j < 4; j++) {
          const int row = r0 + mi * 16 + j;
          outF[(size_t)row * DM + col] = acc[mi][ni][j] + bi;
        }
      }
    }
  } else {
    const int region = col0 >> 11;  // block-uniform: 0=Q, 1=K, 2=V
#pragma unroll
    for (int mi = 0; mi < 4; mi++) {
#pragma unroll
      for (int ni = 0; ni < 4; ni++) {
        const int col = c0 + ni * 16;
        const int c = col & 2047, h = c >> 7, d = c & 127;
#pragma unroll
        for (int j = 0; j < 4; j++) {
          const int row = r0 + mi * 16 + j;
          const int b = row >> 11, s = row & 2047;
          const float v = acc[mi][ni][j];
          if (region == 0) {
            outQ[((size_t)(b * 16 + h) * SEQ + s) * HD + d] = (f16)((v + bq[c]) * QSCALE);
          } else if (region == 1) {
            outK[((size_t)(b * 16 + h) * SEQ + s) * HD + d] = (f16)v;
          } else {
            outV[((size_t)(b * 16 + h) * HD + d) * SEQ + s] = (f16)(v + bv[c]);
          }
        }
      }
    }
  }
}

// Attention: one block = 64 q rows of one (b,h). Two passes over K/V in 64-key
// blocks, double-buffered staging (prefetch issued before compute, drained by
// the end-of-iteration barrier). Swapped QK^T (mfma(K,Q)) so each lane holds 4
// consecutive keys of one q-row -> vectorized f32x4 P stores + f16x4 lP writes.
__global__ __launch_bounds__(256, 2) void attn(const f16* __restrict__ Q,
                                               const f16* __restrict__ Kt,
                                               const f16* __restrict__ Vt,
                                               float* __restrict__ Pout,
                                               f16* __restrict__ Oout) {
  __shared__ __align__(16) f16 smem[36864];  // 72 KiB -> 2 blocks/CU
  // layout: K0 @0, K1 @8192, V0 @16384, V1 @24576, lP @32768 (64x64, swizzled)
  f16* const lP = smem + 32768;

  const int tid = threadIdx.x, w = tid >> 6, l = tid & 63;
  const int t = l >> 4, sl = l & 15, t8 = l >> 3, sl8 = l & 7;
  const int bh = blockIdx.y, q0 = blockIdx.x * 64;
  const f16* Qg = Q + (size_t)bh * SEQ * HD;
  const f16* Kg = Kt + (size_t)bh * SEQ * HD;
  const f16* Vg = Vt + (size_t)bh * HD * SEQ;

  // ---- prologue: stage Q (into V0 slot) + K block 0 (into K0 slot), both async
#pragma unroll
  for (int c = 0; c < 4; c++) {
    const int row = w * 16 + c * 4 + t;
    const int ch = sl ^ (row & 7);
    gload16(Qg + (size_t)(q0 + row) * HD + ch * 8, smem + 16384 + w * 2048 + c * 512);
    gload16(Kg + (size_t)row * HD + ch * 8, smem + w * 2048 + c * 512);
  }
  __syncthreads();

  f16x8 qf[4];
  {
    const int row = w * 16 + sl;
#pragma unroll
    for (int g = 0; g < 4; g++) {
      const int ch = (g * 4 + t) ^ (row & 7);
      qf[g] = *(const f16x8*)&smem[16384 + row * 128 + ch * 8];
    }
  }

  float lsum = 0.0f;

  // ---- pass 1: row sums of exp2(S') (S' already in log2 domain via QSCALE)
  for (int kb = 0; kb < 32; ++kb) {
    f16* const kc = smem + (kb & 1) * 8192;
    if (kb < 31) {
      f16* const kn = smem + ((kb + 1) & 1) * 8192;
#pragma unroll
      for (int c = 0; c < 4; c++) {
        const int row = w * 16 + c * 4 + t;
        const int ch = sl ^ (row & 7);
        gload16(Kg + (size_t)((kb + 1) * 64 + row) * HD + ch * 8, kn + w * 2048 + c * 512);
      }
    }
#pragma unroll
    for (int cb = 0; cb < 4; ++cb) {
      f32x4 s = {0.f, 0.f, 0.f, 0.f};
      const int key = cb * 16 + sl;
#pragma unroll
      for (int g = 0; g < 4; ++g) {
        const int ch = (g * 4 + t) ^ (key & 7);
        f16x8 kf = *(const f16x8*)&kc[key * 128 + ch * 8];
        s = __builtin_amdgcn_mfma_f32_16x16x32_f16(kf, qf[g], s, 0, 0, 0);
      }
#pragma unroll
      for (int j = 0; j < 4; j++) lsum += __builtin_amdgcn_exp2f(s[j]);
    }
    __syncthreads();
  }
  lsum += __shfl_xor(lsum, 16);
  lsum += __shfl_xor(lsum, 32);
  const float inv = 1.0f / lsum;  // full row sum for qrow = w*16 + (l&15)

  // ---- pass 2 prologue: stage K0 + V0
  {
#pragma unroll
    for (int c = 0; c < 4; c++) {
      const int row = w * 16 + c * 4 + t;
      const int ch = sl ^ (row & 7);
      gload16(Kg + (size_t)row * HD + ch * 8, smem + w * 2048 + c * 512);
    }
#pragma unroll
    for (int c = 0; c < 4; c++) {
      const int row = w * 32 + c * 8 + t8;
      const int ch = sl8 ^ (row & 7);
      gload16(Vg + (size_t)row * SEQ + ch * 8, smem + 16384 + w * 2048 + c * 512);
    }
  }
  __syncthreads();

  f32x4 oacc[8] = {};
  const int qrow = w * 16 + sl;
  float* const Prow = Pout + ((size_t)bh * SEQ + q0 + qrow) * SEQ;

  // ---- pass 2: recompute S, write normalized P (f32x4), accumulate PV
  for (int kb = 0; kb < 32; ++kb) {
    f16* const kc = smem + (kb & 1) * 8192;
    f16* const vc = smem + 16384 + (kb & 1) * 8192;
    if (kb < 31) {
      f16* const kn = smem + ((kb + 1) & 1) * 8192;
      f16* const vn = smem + 16384 + ((kb + 1) & 1) * 8192;
#pragma unroll
      for (int c = 0; c < 4; c++) {
        const int row = w * 16 + c * 4 + t;
        const int ch = sl ^ (row & 7);
        gload16(Kg + (size_t)((kb + 1) * 64 + row) * HD + ch * 8, kn + w * 2048 + c * 512);
      }
#pragma unroll
      for (int c = 0; c < 4; c++) {
        const int row = w * 32 + c * 8 + t8;
        const int ch = sl8 ^ (row & 7);
        gload16(Vg + (size_t)row * SEQ + (kb + 1) * 64 + ch * 8, vn + w * 2048 + c * 512);
      }
    }
#pragma unroll
    for (int cb = 0; cb < 4; ++cb) {
      f32x4 s = {0.f, 0.f, 0.f, 0.f};
      const int key = cb * 16 + sl;
#pragma unroll
      for (int g = 0; g < 4; ++g) {
        const int ch = (g * 4 + t) ^ (key & 7);
        f16x8 kf = *(const f16x8*)&kc[key * 128 + ch * 8];
        s = __builtin_amdgcn_mfma_f32_16x16x32_f16(kf, qf[g], s, 0, 0, 0);
      }
      f32x4 p4;
      f16x4 ph;
#pragma unroll
      for (int j = 0; j < 4; j++) {
        const float p = __builtin_amdgcn_exp2f(s[j]) * inv;
        p4[j] = p;
        ph[j] = (f16)p;
      }
      // lane holds 4 consecutive keys (cb*16 + t*4 ..) of row qrow
      *(f32x4*)(Prow + kb * 64 + cb * 16 + t * 4) = p4;
      const int chs = (cb * 2 + (t >> 1)) ^ (qrow & 7);
      *(f16x4*)&lP[qrow * 64 + chs * 8 + (t & 1) * 4] = ph;
    }
    // lP rows are wave-private (rows w*16..w*16+15): no barrier needed,
    // compiler's lgkmcnt wait orders the ds_write -> ds_read.
    f16x8 pf[2];
#pragma unroll
    for (int ks = 0; ks < 2; ++ks) {
      const int ch = (ks * 4 + t) ^ (qrow & 7);
      pf[ks] = *(const f16x8*)&lP[qrow * 64 + ch * 8];
    }
    __builtin_amdgcn_s_setprio(1);
#pragma unroll
    for (int cb = 0; cb < 8; ++cb) {
      const int d = cb * 16 + sl;
#pragma unroll
      for (int ks = 0; ks < 2; ++ks) {
        const int ch = (ks * 4 + t) ^ (d & 7);
        f16x8 vf = *(const f16x8*)&vc[d * 64 + ch * 8];
        oacc[cb] = __builtin_amdgcn_mfma_f32_16x16x32_f16(pf[ks], vf, oacc[cb], 0, 0, 0);
      }
    }
    __builtin_amdgcn_s_setprio(0);
    __syncthreads();
  }

  // O epilogue: [b,h,q,d] -> merged [n][2048] f16 for the final GEMM
  const int b = bh >> 4, h = bh & 15;
#pragma unroll
  for (int cb = 0; cb < 8; ++cb) {
    const int d = cb * 16 + sl;
#pragma unroll
    for (int j = 0; j < 4; j++) {
      const int lrow = w * 16 + t * 4 + j;
      Oout[((size_t)(b * SEQ + q0 + lrow)) * DM + h * HD + d] = (f16)oacc[cb][j];
    }
  }
}

extern "C" void kernel_launch(void* const* d_in, const int* in_sizes, int n_in,
                              void* d_out, int out_size, void* d_ws, size_t ws_size,
                              hipStream_t stream) {
  const float* hs = (const float*)d_in[0];
  const float* Wq = (const float*)d_in[1];
  const float* bq = (const float*)d_in[2];
  const float* Wk = (const float*)d_in[3];
  const float* Wv = (const float*)d_in[4];
  const float* bv = (const float*)d_in[5];
  const float* Wo = (const float*)d_in[6];
  const float* bo = (const float*)d_in[7];
  float* out = (float*)d_out;
  float* Pout = out + (size_t)NT * DM;  // attn_weights region (134M f32)

  // d_ws: 4 x 16 MiB f16 buffers = 64 MiB
  f16* q16 = (f16*)d_ws;
  f16* k16 = q16 + (size_t)NT * DM;
  f16* vt16 = k16 + (size_t)NT * DM;
  f16* ao16 = vt16 + (size_t)NT * DM;
  // hs16 + Wqkv f16 scratch lives inside the P output region (fully
  // overwritten by attn later); Wo16 reuses q16 slot after attn is done.
  f16* hs16 = (f16*)Pout;
  f16* wqkv16 = hs16 + (size_t)NT * DM;  // [6144][2048] f16
  f16* wo16 = q16;

  cvt_f32_f16<<<2048, 256, 0, stream>>>(hs, hs16, NT * DM / 4);
  cvt3_f32_f16<<<2048, 256, 0, stream>>>(Wq, Wk, Wv, wqkv16);

  gemm_bt<3><<<dim3(6144 / 128, NT / 128), 256, 0, stream>>>(
      hs16, wqkv16, bq, bv, nullptr, q16, k16, vt16);

  attn<<<dim3(SEQ / 64, NBH), 256, 0, stream>>>(q16, k16, vt16, Pout, ao16);

  cvt_f32_f16<<<1024, 256, 0, stream>>>(Wo, wo16, DM * DM / 4);
  gemm_bt<0><<<dim3(DM / 128, NT / 128), 256, 0, stream>>>(
      ao16, wo16, bo, nullptr, out, nullptr, nullptr, nullptr);
}

// Round 5
// 413.682 us; speedup vs baseline: 1.1679x; 1.1679x over previous
//
#include <hip/hip_runtime.h>

typedef _Float16 f16;
typedef _Float16 f16x4 __attribute__((ext_vector_type(4)));
typedef _Float16 f16x8 __attribute__((ext_vector_type(8)));
typedef float f32x4 __attribute__((ext_vector_type(4)));

#define DM 2048
#define NT 4096
#define SEQ 2048
#define HD 128
#define NBH 32
// 1/sqrt(128) * log2(e): scores come out in log2 domain -> exp2 is one v_exp_f32
#define QSCALE (0.08838834764831845f * 1.4426950408889634f)

__device__ __forceinline__ void gload16(const f16* g, f16* l) {
  __builtin_amdgcn_global_load_lds(
      (const __attribute__((address_space(1))) void*)g,
      (__attribute__((address_space(3))) void*)l, 16, 0, 0);
}

__global__ __launch_bounds__(256) void cvt_f32_f16(const float* __restrict__ src,
                                                   f16* __restrict__ dst, int n4) {
  int i = blockIdx.x * 256 + threadIdx.x;
  int st = gridDim.x * 256;
  for (; i < n4; i += st) {
    float4 v = ((const float4*)src)[i];
    f16x4 h = {(f16)v.x, (f16)v.y, (f16)v.z, (f16)v.w};
    ((f16x4*)dst)[i] = h;
  }
}

// concatenated weight convert: dst regions of 2^20 f32x4 elems each
__global__ __launch_bounds__(256) void cvt3_f32_f16(const float* __restrict__ s0,
                                                    const float* __restrict__ s1,
                                                    const float* __restrict__ s2,
                                                    f16* __restrict__ dst) {
  int i = blockIdx.x * 256 + threadIdx.x;
  int st = gridDim.x * 256;
  for (; i < 3 * 1048576; i += st) {
    const int r = i >> 20, j = i & 1048575;
    const float* s = (r == 0) ? s0 : ((r == 1) ? s1 : s2);
    float4 v = ((const float4*)s)[j];
    f16x4 h = {(f16)v.x, (f16)v.y, (f16)v.z, (f16)v.w};
    ((f16x4*)dst)[i] = h;
  }
}

// C = A(4096x2048) * B^T; B row-major [N][2048]. 128x128 tile, BK=32, 2-phase
// dbuf, XCD-swizzled block mapping, LDS-staged coalesced f16 epilogues.
// MODE 0: O-projection, f32 out [row][2048] + bias (direct stores, 64B runs)
// MODE 3: fused QKV (N=6144): region = col>>11:
//   0 = Q: plain [row][2048] f16, (v+bq)*QSCALE
//   1 = K: plain [row][2048] f16
//   2 = V: transposed [bh][d][s] f16, v+bv  (transpose via LDS)
template <int MODE>
__global__ __launch_bounds__(256, 2) void gemm_bt(const f16* __restrict__ A,
                                                  const f16* __restrict__ B,
                                                  const float* __restrict__ bias1,
                                                  const float* __restrict__ bias2,
                                                  float* __restrict__ outF,
                                                  f16* __restrict__ outQ,
                                                  f16* __restrict__ outK,
                                                  f16* __restrict__ outV) {
  // 16 KB lA dbuf + 16 KB lB dbuf; epilogue reuses all 36 KB as ep[128][136]
  __shared__ __align__(16) f16 smem[128 * 136];
  f16* const lA = smem;          // [2][128*32]
  f16* const lB = smem + 8192;   // [2][128*32]

  const int tid = threadIdx.x;
  const int w = tid >> 6, l = tid & 63;
  const int wr = w >> 1, wc = w & 1;

  // XCD-aware swizzle (bijective: grid size % 8 == 0)
  const int nbx = gridDim.x;
  const int flat = blockIdx.y * nbx + blockIdx.x;
  const int chunk = (nbx * gridDim.y) >> 3;
  const int swz = (flat & 7) * chunk + (flat >> 3);
  const int row0 = (swz / nbx) * 128, col0 = (swz % nbx) * 128;

  f32x4 acc[4][4] = {};

  const int srow = w * 32 + (l >> 2);
  const int sk = (l & 3) * 8;
  const f16* gA = A + (size_t)(row0 + srow) * DM + sk;
  const f16* gB = B + (size_t)(col0 + srow) * DM + sk;

  {
    f16* sA = lA + w * 1024;
    f16* sB = lB + w * 1024;
    gload16(gA, sA);
    gload16(gA + 16 * DM, sA + 512);
    gload16(gB, sB);
    gload16(gB + 16 * DM, sB + 512);
  }

  int cur = 0;
  for (int k0 = 0; k0 < DM; k0 += 32) {
    __syncthreads();
    if (k0 + 32 < DM) {
      f16* sA = lA + (cur ^ 1) * 4096 + w * 1024;
      f16* sB = lB + (cur ^ 1) * 4096 + w * 1024;
      gload16(gA + k0 + 32, sA);
      gload16(gA + k0 + 32 + 16 * DM, sA + 512);
      gload16(gB + k0 + 32, sB);
      gload16(gB + k0 + 32 + 16 * DM, sB + 512);
    }
    f16x8 af[4], bf[4];
#pragma unroll
    for (int i = 0; i < 4; i++)
      af[i] = *(const f16x8*)&lA[cur * 4096 + (wr * 64 + i * 16 + (l & 15)) * 32 + (l >> 4) * 8];
#pragma unroll
    for (int i = 0; i < 4; i++)
      bf[i] = *(const f16x8*)&lB[cur * 4096 + (wc * 64 + i * 16 + (l & 15)) * 32 + (l >> 4) * 8];
#pragma unroll
    for (int mi = 0; mi < 4; mi++)
#pragma unroll
      for (int ni = 0; ni < 4; ni++)
        acc[mi][ni] = __builtin_amdgcn_mfma_f32_16x16x32_f16(af[mi], bf[ni], acc[mi][ni], 0, 0, 0);
    cur ^= 1;
  }

  const int rl0 = wr * 64 + (l >> 4) * 4;  // local row base
  const int cl0 = wc * 64 + (l & 15);      // local col base
  if constexpr (MODE == 0) {
#pragma unroll
    for (int mi = 0; mi < 4; mi++) {
#pragma unroll
      for (int ni = 0; ni < 4; ni++) {
        const int col = col0 + cl0 + ni * 16;
        const float bi = bias1[col];
#pragma unroll
        for (int j = 0; j < 4; j++) {
          const int row = row0 + rl0 + mi * 16 + j;
          outF[(size_t)row * DM + col] = acc[mi][ni][j] + bi;
        }
      }
    }
  } else {
    const int region = col0 >> 11;       // block-uniform: 0=Q, 1=K, 2=V
    const int c2 = col0 & 2047;          // col base within region
    __syncthreads();                     // all waves done with lA/lB reads
#pragma unroll
    for (int mi = 0; mi < 4; mi++) {
#pragma unroll
      for (int ni = 0; ni < 4; ni++) {
        const int cl = cl0 + ni * 16;
        const int cg = c2 + cl;
#pragma unroll
        for (int j = 0; j < 4; j++) {
          const int rl = rl0 + mi * 16 + j;
          const float v = acc[mi][ni][j];
          f16 hv;
          if (region == 0)
            hv = (f16)((v + bias1[cg]) * QSCALE);
          else if (region == 1)
            hv = (f16)v;
          else
            hv = (f16)(v + bias2[cg]);
          if (region == 2)
            smem[cl * 136 + rl] = hv;    // transposed: ep[d][s]
          else
            smem[rl * 136 + cl] = hv;    // ep[row][col]
        }
      }
    }
    __syncthreads();
    // coalesced store: 2048 f16x8 chunks, 8 per thread
    if (region == 2) {
      const int b = row0 >> 11, h = c2 >> 7, s0 = row0 & 2047;
      f16* const dst = outV + ((size_t)(b * 16 + h) * HD) * SEQ + s0;
#pragma unroll
      for (int it = 0; it < 8; it++) {
        const int ck = it * 256 + tid;
        const int rr = ck >> 4, cc = (ck & 15) * 8;  // rr=d, cc=s offset
        *(f16x8*)&dst[(size_t)rr * SEQ + cc] = *(const f16x8*)&smem[rr * 136 + cc];
      }
    } else {
      f16* const dst = (region == 0 ? outQ : outK) + (size_t)row0 * DM + c2;
#pragma unroll
      for (int it = 0; it < 8; it++) {
        const int ck = it * 256 + tid;
        const int rr = ck >> 4, cc = (ck & 15) * 8;
        *(f16x8*)&dst[(size_t)rr * DM + cc] = *(const f16x8*)&smem[rr * 136 + cc];
      }
    }
  }
}

// Attention: one block = 64 q rows of one (b,h). Two passes over K/V in 64-key
// blocks, double-buffered staging. Swapped QK^T (mfma(K,Q)): lane holds 4
// consecutive keys of one q-row -> f32x4 nontemporal P stores + f16x4 lP.
// Q/K in plain [b*2048+s][2048] layout (head h at cols h*128..); V [bh][d][s].
__global__ __launch_bounds__(256, 2) void attn(const f16* __restrict__ Q,
                                               const f16* __restrict__ Kt,
                                               const f16* __restrict__ Vt,
                                               float* __restrict__ Pout,
                                               f16* __restrict__ Oout) {
  __shared__ __align__(16) f16 smem[36864];  // 72 KiB -> 2 blocks/CU
  // layout: K0 @0, K1 @8192, V0 @16384, V1 @24576, lP @32768 (64x64, swizzled)
  f16* const lP = smem + 32768;

  const int tid = threadIdx.x, w = tid >> 6, l = tid & 63;
  const int t = l >> 4, sl = l & 15, t8 = l >> 3, sl8 = l & 7;

  // XCD swizzle: 1024 blocks, each XCD gets 4 whole (b,h) -> K/V L2-resident
  const int flat = blockIdx.y * gridDim.x + blockIdx.x;
  const int swz = (flat & 7) * 128 + (flat >> 3);
  const int bh = swz >> 5, q0 = (swz & 31) * 64;

  const int b = bh >> 4, h = bh & 15;
  const f16* Qg = Q + (size_t)(b * SEQ) * DM + h * HD;  // row stride DM
  const f16* Kg = Kt + (size_t)(b * SEQ) * DM + h * HD;
  const f16* Vg = Vt + (size_t)bh * HD * SEQ;

  // ---- prologue: stage Q (into V0 slot) + K block 0 (into K0 slot), async
#pragma unroll
  for (int c = 0; c < 4; c++) {
    const int row = w * 16 + c * 4 + t;
    const int ch = sl ^ (row & 7);
    gload16(Qg + (size_t)(q0 + row) * DM + ch * 8, smem + 16384 + w * 2048 + c * 512);
    gload16(Kg + (size_t)row * DM + ch * 8, smem + w * 2048 + c * 512);
  }
  __syncthreads();

  f16x8 qf[4];
  {
    const int row = w * 16 + sl;
#pragma unroll
    for (int g = 0; g < 4; g++) {
      const int ch = (g * 4 + t) ^ (row & 7);
      qf[g] = *(const f16x8*)&smem[16384 + row * 128 + ch * 8];
    }
  }

  float lsum = 0.0f;

  // ---- pass 1: row sums of exp2(S') (S' in log2 domain via QSCALE)
  for (int kb = 0; kb < 32; ++kb) {
    f16* const kc = smem + (kb & 1) * 8192;
    if (kb < 31) {
      f16* const kn = smem + ((kb + 1) & 1) * 8192;
#pragma unroll
      for (int c = 0; c < 4; c++) {
        const int row = w * 16 + c * 4 + t;
        const int ch = sl ^ (row & 7);
        gload16(Kg + (size_t)((kb + 1) * 64 + row) * DM + ch * 8, kn + w * 2048 + c * 512);
      }
    }
#pragma unroll
    for (int cb = 0; cb < 4; ++cb) {
      f32x4 s = {0.f, 0.f, 0.f, 0.f};
      const int key = cb * 16 + sl;
#pragma unroll
      for (int g = 0; g < 4; ++g) {
        const int ch = (g * 4 + t) ^ (key & 7);
        f16x8 kf = *(const f16x8*)&kc[key * 128 + ch * 8];
        s = __builtin_amdgcn_mfma_f32_16x16x32_f16(kf, qf[g], s, 0, 0, 0);
      }
#pragma unroll
      for (int j = 0; j < 4; j++) lsum += __builtin_amdgcn_exp2f(s[j]);
    }
    __syncthreads();
  }
  lsum += __shfl_xor(lsum, 16);
  lsum += __shfl_xor(lsum, 32);
  const float inv = 1.0f / lsum;  // full row sum for qrow = w*16 + (l&15)

  // ---- pass 2 prologue: stage K0 + V0
  {
#pragma unroll
    for (int c = 0; c < 4; c++) {
      const int row = w * 16 + c * 4 + t;
      const int ch = sl ^ (row & 7);
      gload16(Kg + (size_t)row * DM + ch * 8, smem + w * 2048 + c * 512);
    }
#pragma unroll
    for (int c = 0; c < 4; c++) {
      const int row = w * 32 + c * 8 + t8;
      const int ch = sl8 ^ (row & 7);
      gload16(Vg + (size_t)row * SEQ + ch * 8, smem + 16384 + w * 2048 + c * 512);
    }
  }
  __syncthreads();

  f32x4 oacc[8] = {};
  const int qrow = w * 16 + sl;
  float* const Prow = Pout + ((size_t)bh * SEQ + q0 + qrow) * SEQ;

  // ---- pass 2: recompute S, write normalized P (nt f32x4), accumulate PV
  for (int kb = 0; kb < 32; ++kb) {
    f16* const kc = smem + (kb & 1) * 8192;
    f16* const vc = smem + 16384 + (kb & 1) * 8192;
    if (kb < 31) {
      f16* const kn = smem + ((kb + 1) & 1) * 8192;
      f16* const vn = smem + 16384 + ((kb + 1) & 1) * 8192;
#pragma unroll
      for (int c = 0; c < 4; c++) {
        const int row = w * 16 + c * 4 + t;
        const int ch = sl ^ (row & 7);
        gload16(Kg + (size_t)((kb + 1) * 64 + row) * DM + ch * 8, kn + w * 2048 + c * 512);
      }
#pragma unroll
      for (int c = 0; c < 4; c++) {
        const int row = w * 32 + c * 8 + t8;
        const int ch = sl8 ^ (row & 7);
        gload16(Vg + (size_t)row * SEQ + (kb + 1) * 64 + ch * 8, vn + w * 2048 + c * 512);
      }
    }
#pragma unroll
    for (int cb = 0; cb < 4; ++cb) {
      f32x4 s = {0.f, 0.f, 0.f, 0.f};
      const int key = cb * 16 + sl;
#pragma unroll
      for (int g = 0; g < 4; ++g) {
        const int ch = (g * 4 + t) ^ (key & 7);
        f16x8 kf = *(const f16x8*)&kc[key * 128 + ch * 8];
        s = __builtin_amdgcn_mfma_f32_16x16x32_f16(kf, qf[g], s, 0, 0, 0);
      }
      f32x4 p4;
      f16x4 ph;
#pragma unroll
      for (int j = 0; j < 4; j++) {
        const float p = __builtin_amdgcn_exp2f(s[j]) * inv;
        p4[j] = p;
        ph[j] = (f16)p;
      }
      __builtin_nontemporal_store(p4, (f32x4*)(Prow + kb * 64 + cb * 16 + t * 4));
      const int chs = (cb * 2 + (t >> 1)) ^ (qrow & 7);
      *(f16x4*)&lP[qrow * 64 + chs * 8 + (t & 1) * 4] = ph;
    }
    // lP rows are wave-private: ds ordering via lgkmcnt, no barrier needed
    f16x8 pf[2];
#pragma unroll
    for (int ks = 0; ks < 2; ++ks) {
      const int ch = (ks * 4 + t) ^ (qrow & 7);
      pf[ks] = *(const f16x8*)&lP[qrow * 64 + ch * 8];
    }
    __builtin_amdgcn_s_setprio(1);
#pragma unroll
    for (int cb = 0; cb < 8; ++cb) {
      const int d = cb * 16 + sl;
#pragma unroll
      for (int ks = 0; ks < 2; ++ks) {
        const int ch = (ks * 4 + t) ^ (d & 7);
        f16x8 vf = *(const f16x8*)&vc[d * 64 + ch * 8];
        oacc[cb] = __builtin_amdgcn_mfma_f32_16x16x32_f16(pf[ks], vf, oacc[cb], 0, 0, 0);
      }
    }
    __builtin_amdgcn_s_setprio(0);
    __syncthreads();
  }

  // O epilogue: [b,h,q,d] -> merged [n][2048] f16 for the final GEMM
#pragma unroll
  for (int cb = 0; cb < 8; ++cb) {
    const int d = cb * 16 + sl;
#pragma unroll
    for (int j = 0; j < 4; j++) {
      const int lrow = w * 16 + t * 4 + j;
      Oout[((size_t)(b * SEQ + q0 + lrow)) * DM + h * HD + d] = (f16)oacc[cb][j];
    }
  }
}

extern "C" void kernel_launch(void* const* d_in, const int* in_sizes, int n_in,
                              void* d_out, int out_size, void* d_ws, size_t ws_size,
                              hipStream_t stream) {
  const float* hs = (const float*)d_in[0];
  const float* Wq = (const float*)d_in[1];
  const float* bq = (const float*)d_in[2];
  const float* Wk = (const float*)d_in[3];
  const float* Wv = (const float*)d_in[4];
  const float* bv = (const float*)d_in[5];
  const float* Wo = (const float*)d_in[6];
  const float* bo = (const float*)d_in[7];
  float* out = (float*)d_out;
  float* Pout = out + (size_t)NT * DM;  // attn_weights region (134M f32)

  // d_ws: 4 x 16 MiB f16 buffers = 64 MiB
  f16* q16 = (f16*)d_ws;
  f16* k16 = q16 + (size_t)NT * DM;
  f16* vt16 = k16 + (size_t)NT * DM;
  f16* ao16 = vt16 + (size_t)NT * DM;
  // hs16 + Wqkv f16 scratch lives inside the P output region (fully
  // overwritten by attn later); Wo16 reuses q16 slot after attn is done.
  f16* hs16 = (f16*)Pout;
  f16* wqkv16 = hs16 + (size_t)NT * DM;  // [6144][2048] f16
  f16* wo16 = q16;

  cvt_f32_f16<<<2048, 256, 0, stream>>>(hs, hs16, NT * DM / 4);
  cvt3_f32_f16<<<2048, 256, 0, stream>>>(Wq, Wk, Wv, wqkv16);

  gemm_bt<3><<<dim3(6144 / 128, NT / 128), 256, 0, stream>>>(
      hs16, wqkv16, bq, bv, nullptr, q16, k16, vt16);

  attn<<<dim3(SEQ / 64, NBH), 256, 0, stream>>>(q16, k16, vt16, Pout, ao16);

  cvt_f32_f16<<<1024, 256, 0, stream>>>(Wo, wo16, DM * DM / 4);
  gemm_bt<0><<<dim3(DM / 128, NT / 128), 256, 0, stream>>>(
      ao16, wo16, bo, nullptr, out, nullptr, nullptr, nullptr);
}

// Round 6
// 388.421 us; speedup vs baseline: 1.2439x; 1.0650x over previous
//
#include <hip/hip_runtime.h>

typedef _Float16 f16;
typedef _Float16 f16x4 __attribute__((ext_vector_type(4)));
typedef _Float16 f16x8 __attribute__((ext_vector_type(8)));
typedef float f32x4 __attribute__((ext_vector_type(4)));

#define DM 2048
#define NT 4096
#define SEQ 2048
#define HD 128
#define NBH 32
// 1/sqrt(128) * log2(e): scores come out in log2 domain -> exp2 is one v_exp_f32
#define QSCALE (0.08838834764831845f * 1.4426950408889634f)

__device__ __forceinline__ void gload16(const f16* g, f16* l) {
  __builtin_amdgcn_global_load_lds(
      (const __attribute__((address_space(1))) void*)g,
      (__attribute__((address_space(3))) void*)l, 16, 0, 0);
}

#define LGKM0                                         \
  asm volatile("s_waitcnt lgkmcnt(0)" ::: "memory"); \
  __builtin_amdgcn_sched_barrier(0)
#define VMC6                                         \
  asm volatile("s_waitcnt vmcnt(6)" ::: "memory");   \
  __builtin_amdgcn_sched_barrier(0)
#define VMC0                                         \
  asm volatile("s_waitcnt vmcnt(0)" ::: "memory");   \
  __builtin_amdgcn_sched_barrier(0)

__global__ __launch_bounds__(256) void cvt_f32_f16(const float* __restrict__ src,
                                                   f16* __restrict__ dst, int n4) {
  int i = blockIdx.x * 256 + threadIdx.x;
  int st = gridDim.x * 256;
  for (; i < n4; i += st) {
    float4 v = ((const float4*)src)[i];
    f16x4 h = {(f16)v.x, (f16)v.y, (f16)v.z, (f16)v.w};
    ((f16x4*)dst)[i] = h;
  }
}

// concatenated weight convert: dst regions of 2^20 f32x4 elems each
__global__ __launch_bounds__(256) void cvt3_f32_f16(const float* __restrict__ s0,
                                                    const float* __restrict__ s1,
                                                    const float* __restrict__ s2,
                                                    f16* __restrict__ dst) {
  int i = blockIdx.x * 256 + threadIdx.x;
  int st = gridDim.x * 256;
  for (; i < 3 * 1048576; i += st) {
    const int r = i >> 20, j = i & 1048575;
    const float* s = (r == 0) ? s0 : ((r == 1) ? s1 : s2);
    float4 v = ((const float4*)s)[j];
    f16x4 h = {(f16)v.x, (f16)v.y, (f16)v.z, (f16)v.w};
    ((f16x4*)dst)[i] = h;
  }
}

// ============================================================================
// 8-phase-style GEMM: C = A(4096x2048) * B^T, B row-major [N][2048].
// Tile BM=128 x BN=256, BK=64, 8 waves (2M x 4N), wave tile 64x64.
// Triple-buffered LDS (144 KiB), staging issued 2 K-tiles ahead, counted
// vmcnt(6) at tile boundaries (T3+T4), XOR chunk-swizzle on LDS rows (T2),
// setprio around MFMA clusters (T5). 4 phases per K-tile.
// MODE 0: O-projection, f32 out [row][2048] + bias1 (direct stores)
// MODE 3: fused QKV (N=6144): region = col0>>11:
//   0 = Q: [row][2048] f16, (v+bias1)*QSCALE
//   1 = K: [row][2048] f16
//   2 = V: transposed [bh][d][s] f16, v+bias2 (transpose via LDS)
// ============================================================================
template <int MODE>
__global__ __launch_bounds__(512, 2) void gemm8(const f16* __restrict__ A,
                                                const f16* __restrict__ Bm,
                                                const float* __restrict__ bias1,
                                                const float* __restrict__ bias2,
                                                float* __restrict__ outF,
                                                f16* __restrict__ outQ,
                                                f16* __restrict__ outK,
                                                f16* __restrict__ outV) {
  // A: 3 bufs x 16 KiB @ f16 idx 0/8192/16384; B: 3 bufs x 32 KiB @ 24576+i*16384
  __shared__ __align__(16) f16 smem[73728];  // 144 KiB -> 1 block/CU, 8 waves
  const int tid = threadIdx.x;
  const int w = tid >> 6, l = tid & 63;
  const int wr = w >> 2, wc = w & 3;  // 2M x 4N wave grid
  const int sl = l & 15, t4 = l >> 4;

  // XCD-aware swizzle (total blocks % 8 == 0 -> bijective)
  const int nbx = gridDim.x;
  const int flat = blockIdx.y * nbx + blockIdx.x;
  const int chunk = (nbx * gridDim.y) >> 3;
  const int swz = (flat & 7) * chunk + (flat >> 3);
  const int row0 = (swz / nbx) * 128, col0 = (swz % nbx) * 256;

  f32x4 acc[4][4] = {};

  // staging: each gload16 covers 8 rows x 64 f16 (1 KiB), wave-uniform LDS base.
  // global source pre-swizzled: chunk c of row r loaded from chunk c^(r&7).
  const int sr8 = l >> 3;
  const int sch = (l & 7) ^ (sr8 & 7);
  const f16* gA0 = A + (size_t)(row0 + w * 8 + sr8) * DM + sch * 8;
  const f16* gB0 = Bm + (size_t)(col0 + w * 8 + sr8) * DM + sch * 8;

#define SA(tb, kt, r) \
  gload16(gA0 + (size_t)(r) * 64 * DM + (kt) * 64, smem + (tb) * 8192 + (r) * 4096 + w * 512)
#define SB(tb, kt, r)                                  \
  gload16(gB0 + (size_t)(r) * 64 * DM + (kt) * 64,    \
          smem + 24576 + (tb) * 16384 + (r) * 4096 + w * 512)
#define MF(mi, ni, av, bv) \
  acc[mi][ni] = __builtin_amdgcn_mfma_f32_16x16x32_f16(av, bv, acc[mi][ni], 0, 0, 0)

  // fragment read offsets: row = base + i*16 + sl (base mult of 16) -> row&7 = sl&7
  const int sx = sl & 7;
  const int sk0 = (t4 ^ sx) * 8;        // kk=0 chunk slot
  const int sk1 = ((4 + t4) ^ sx) * 8;  // kk=1 chunk slot
  const int arow = (wr * 64 + sl) * 64;
  const int brow = (wc * 64 + sl) * 64;

  // ---- prologue: stage tiles 0 and 1
  SA(0, 0, 0); SA(0, 0, 1);
  SB(0, 0, 0); SB(0, 0, 1); SB(0, 0, 2); SB(0, 0, 3);
  SA(1, 1, 0); SA(1, 1, 1);
  SB(1, 1, 0); SB(1, 1, 1); SB(1, 1, 2); SB(1, 1, 3);
  VMC6;  // tile 0's 6 loads complete (tile 1's 6 may be outstanding)
  __builtin_amdgcn_s_barrier();

  int cur = 0;
#pragma unroll 1
  for (int t = 0; t < 32; ++t) {
    const int nb = (cur == 0) ? 2 : cur - 1;  // (t+2)%3 — buffer of tile t-1, reads done
    const bool pf = (t + 2 < 32);
    const int ab = cur * 8192;
    const int bb = 24576 + cur * 16384;
    f16x8 b0, b1, b2, b3, a0, a1;

    // ---- phase 0: read bf(kk0)+af01(kk0); stage A(t+2); MFMA mi0-1 kk0
    b0 = *(const f16x8*)&smem[bb + brow + sk0];
    b1 = *(const f16x8*)&smem[bb + brow + 1024 + sk0];
    b2 = *(const f16x8*)&smem[bb + brow + 2048 + sk0];
    b3 = *(const f16x8*)&smem[bb + brow + 3072 + sk0];
    a0 = *(const f16x8*)&smem[ab + arow + sk0];
    a1 = *(const f16x8*)&smem[ab + arow + 1024 + sk0];
    if (pf) { SA(nb, t + 2, 0); SA(nb, t + 2, 1); }
    __builtin_amdgcn_s_barrier();
    LGKM0;
    __builtin_amdgcn_s_setprio(1);
    MF(0, 0, a0, b0); MF(0, 1, a0, b1); MF(0, 2, a0, b2); MF(0, 3, a0, b3);
    MF(1, 0, a1, b0); MF(1, 1, a1, b1); MF(1, 2, a1, b2); MF(1, 3, a1, b3);
    __builtin_amdgcn_s_setprio(0);
    __builtin_amdgcn_s_barrier();

    // ---- phase 1: read af23(kk0); stage B01(t+2); MFMA mi2-3 kk0
    a0 = *(const f16x8*)&smem[ab + arow + 2048 + sk0];
    a1 = *(const f16x8*)&smem[ab + arow + 3072 + sk0];
    if (pf) { SB(nb, t + 2, 0); SB(nb, t + 2, 1); }
    __builtin_amdgcn_s_barrier();
    LGKM0;
    __builtin_amdgcn_s_setprio(1);
    MF(2, 0, a0, b0); MF(2, 1, a0, b1); MF(2, 2, a0, b2); MF(2, 3, a0, b3);
    MF(3, 0, a1, b0); MF(3, 1, a1, b1); MF(3, 2, a1, b2); MF(3, 3, a1, b3);
    __builtin_amdgcn_s_setprio(0);
    __builtin_amdgcn_s_barrier();

    // ---- phase 2: read bf(kk1)+af01(kk1); stage B23(t+2); MFMA mi0-1 kk1
    b0 = *(const f16x8*)&smem[bb + brow + sk1];
    b1 = *(const f16x8*)&smem[bb + brow + 1024 + sk1];
    b2 = *(const f16x8*)&smem[bb + brow + 2048 + sk1];
    b3 = *(const f16x8*)&smem[bb + brow + 3072 + sk1];
    a0 = *(const f16x8*)&smem[ab + arow + sk1];
    a1 = *(const f16x8*)&smem[ab + arow + 1024 + sk1];
    if (pf) { SB(nb, t + 2, 2); SB(nb, t + 2, 3); }
    __builtin_amdgcn_s_barrier();
    LGKM0;
    __builtin_amdgcn_s_setprio(1);
    MF(0, 0, a0, b0); MF(0, 1, a0, b1); MF(0, 2, a0, b2); MF(0, 3, a0, b3);
    MF(1, 0, a1, b0); MF(1, 1, a1, b1); MF(1, 2, a1, b2); MF(1, 3, a1, b3);
    __builtin_amdgcn_s_setprio(0);
    __builtin_amdgcn_s_barrier();

    // ---- phase 3: read af23(kk1); MFMA mi2-3 kk1; boundary vmcnt
    a0 = *(const f16x8*)&smem[ab + arow + 2048 + sk1];
    a1 = *(const f16x8*)&smem[ab + arow + 3072 + sk1];
    __builtin_amdgcn_s_barrier();
    LGKM0;
    __builtin_amdgcn_s_setprio(1);
    MF(2, 0, a0, b0); MF(2, 1, a0, b1); MF(2, 2, a0, b2); MF(2, 3, a0, b3);
    MF(3, 0, a1, b0); MF(3, 1, a1, b1); MF(3, 2, a1, b2); MF(3, 3, a1, b3);
    __builtin_amdgcn_s_setprio(0);
    if (t < 30) { VMC6; } else { VMC0; }
    __builtin_amdgcn_s_barrier();
    cur = (cur == 2) ? 0 : cur + 1;
  }
#undef SA
#undef SB
#undef MF

  const int rl0 = wr * 64 + t4 * 4;
  const int cl0 = wc * 64 + sl;
  if constexpr (MODE == 0) {
#pragma unroll
    for (int mi = 0; mi < 4; mi++) {
#pragma unroll
      for (int ni = 0; ni < 4; ni++) {
        const int col = col0 + cl0 + ni * 16;
        const float bi = bias1[col];
#pragma unroll
        for (int j = 0; j < 4; j++) {
          const int row = row0 + rl0 + mi * 16 + j;
          outF[(size_t)row * DM + col] = acc[mi][ni][j] + bi;
        }
      }
    }
  } else {
    const int region = col0 >> 11;  // block-uniform (2048 % 256 == 0): 0=Q,1=K,2=V
    const int c2 = col0 & 2047;
    __syncthreads();
    if (region == 2) {
      // transposed ep[256][136]: ep[d-col][s-row]
#pragma unroll
      for (int mi = 0; mi < 4; mi++)
#pragma unroll
        for (int ni = 0; ni < 4; ni++) {
          const int cl = cl0 + ni * 16;
          const float bb2 = bias2[c2 + cl];
#pragma unroll
          for (int j = 0; j < 4; j++)
            smem[cl * 136 + rl0 + mi * 16 + j] = (f16)(acc[mi][ni][j] + bb2);
        }
      __syncthreads();
      const int b = row0 >> 11, s0 = row0 & 2047;
#pragma unroll
      for (int it = 0; it < 8; ++it) {
        const int ck = it * 512 + tid;
        const int ci = ck >> 4, cc = (ck & 15) * 8;
        const int dg = c2 + ci;
        *(f16x8*)&outV[((size_t)(b * 16 + (dg >> 7)) * HD + (dg & 127)) * SEQ + s0 + cc] =
            *(const f16x8*)&smem[ci * 136 + cc];
      }
    } else {
      // ep[128][264]
#pragma unroll
      for (int mi = 0; mi < 4; mi++)
#pragma unroll
        for (int ni = 0; ni < 4; ni++) {
          const int cl = cl0 + ni * 16;
          const int cg = c2 + cl;
          const float badd = (region == 0) ? bias1[cg] : 0.0f;
#pragma unroll
          for (int j = 0; j < 4; j++) {
            float v = acc[mi][ni][j] + badd;
            if (region == 0) v *= QSCALE;
            smem[(rl0 + mi * 16 + j) * 264 + cl] = (f16)v;
          }
        }
      __syncthreads();
      f16* const dst = (region == 0 ? outQ : outK) + (size_t)row0 * DM + c2;
#pragma unroll
      for (int it = 0; it < 8; ++it) {
        const int ck = it * 512 + tid;
        const int rr = ck >> 5, cc = (ck & 31) * 8;
        *(f16x8*)&dst[(size_t)rr * DM + cc] = *(const f16x8*)&smem[rr * 264 + cc];
      }
    }
  }
}

// Attention: one block = 64 q rows of one (b,h). Two passes over K/V in 64-key
// blocks, double-buffered staging. Swapped QK^T (mfma(K,Q)): lane holds 4
// consecutive keys of one q-row -> f32x4 nontemporal P stores + f16x4 lP.
// Q/K in plain [b*2048+s][2048] layout (head h at cols h*128..); V [bh][d][s].
__global__ __launch_bounds__(256, 2) void attn(const f16* __restrict__ Q,
                                               const f16* __restrict__ Kt,
                                               const f16* __restrict__ Vt,
                                               float* __restrict__ Pout,
                                               f16* __restrict__ Oout) {
  __shared__ __align__(16) f16 smem[36864];  // 72 KiB -> 2 blocks/CU
  // layout: K0 @0, K1 @8192, V0 @16384, V1 @24576, lP @32768 (64x64, swizzled)
  f16* const lP = smem + 32768;

  const int tid = threadIdx.x, w = tid >> 6, l = tid & 63;
  const int t = l >> 4, sl = l & 15, t8 = l >> 3, sl8 = l & 7;

  // XCD swizzle: 1024 blocks, each XCD gets 4 whole (b,h) -> K/V L2-resident
  const int flat = blockIdx.y * gridDim.x + blockIdx.x;
  const int swz = (flat & 7) * 128 + (flat >> 3);
  const int bh = swz >> 5, q0 = (swz & 31) * 64;

  const int b = bh >> 4, h = bh & 15;
  const f16* Qg = Q + (size_t)(b * SEQ) * DM + h * HD;  // row stride DM
  const f16* Kg = Kt + (size_t)(b * SEQ) * DM + h * HD;
  const f16* Vg = Vt + (size_t)bh * HD * SEQ;

  // ---- prologue: stage Q (into V0 slot) + K block 0 (into K0 slot), async
#pragma unroll
  for (int c = 0; c < 4; c++) {
    const int row = w * 16 + c * 4 + t;
    const int ch = sl ^ (row & 7);
    gload16(Qg + (size_t)(q0 + row) * DM + ch * 8, smem + 16384 + w * 2048 + c * 512);
    gload16(Kg + (size_t)row * DM + ch * 8, smem + w * 2048 + c * 512);
  }
  __syncthreads();

  f16x8 qf[4];
  {
    const int row = w * 16 + sl;
#pragma unroll
    for (int g = 0; g < 4; g++) {
      const int ch = (g * 4 + t) ^ (row & 7);
      qf[g] = *(const f16x8*)&smem[16384 + row * 128 + ch * 8];
    }
  }

  float lsum = 0.0f;

  // ---- pass 1: row sums of exp2(S') (S' in log2 domain via QSCALE)
  for (int kb = 0; kb < 32; ++kb) {
    f16* const kc = smem + (kb & 1) * 8192;
    if (kb < 31) {
      f16* const kn = smem + ((kb + 1) & 1) * 8192;
#pragma unroll
      for (int c = 0; c < 4; c++) {
        const int row = w * 16 + c * 4 + t;
        const int ch = sl ^ (row & 7);
        gload16(Kg + (size_t)((kb + 1) * 64 + row) * DM + ch * 8, kn + w * 2048 + c * 512);
      }
    }
#pragma unroll
    for (int cb = 0; cb < 4; ++cb) {
      f32x4 s = {0.f, 0.f, 0.f, 0.f};
      const int key = cb * 16 + sl;
#pragma unroll
      for (int g = 0; g < 4; ++g) {
        const int ch = (g * 4 + t) ^ (key & 7);
        f16x8 kf = *(const f16x8*)&kc[key * 128 + ch * 8];
        s = __builtin_amdgcn_mfma_f32_16x16x32_f16(kf, qf[g], s, 0, 0, 0);
      }
#pragma unroll
      for (int j = 0; j < 4; j++) lsum += __builtin_amdgcn_exp2f(s[j]);
    }
    __syncthreads();
  }
  lsum += __shfl_xor(lsum, 16);
  lsum += __shfl_xor(lsum, 32);
  const float inv = 1.0f / lsum;  // full row sum for qrow = w*16 + (l&15)

  // ---- pass 2 prologue: stage K0 + V0
  {
#pragma unroll
    for (int c = 0; c < 4; c++) {
      const int row = w * 16 + c * 4 + t;
      const int ch = sl ^ (row & 7);
      gload16(Kg + (size_t)row * DM + ch * 8, smem + w * 2048 + c * 512);
    }
#pragma unroll
    for (int c = 0; c < 4; c++) {
      const int row = w * 32 + c * 8 + t8;
      const int ch = sl8 ^ (row & 7);
      gload16(Vg + (size_t)row * SEQ + ch * 8, smem + 16384 + w * 2048 + c * 512);
    }
  }
  __syncthreads();

  f32x4 oacc[8] = {};
  const int qrow = w * 16 + sl;
  float* const Prow = Pout + ((size_t)bh * SEQ + q0 + qrow) * SEQ;

  // ---- pass 2: recompute S, write normalized P (nt f32x4), accumulate PV
  for (int kb = 0; kb < 32; ++kb) {
    f16* const kc = smem + (kb & 1) * 8192;
    f16* const vc = smem + 16384 + (kb & 1) * 8192;
    if (kb < 31) {
      f16* const kn = smem + ((kb + 1) & 1) * 8192;
      f16* const vn = smem + 16384 + ((kb + 1) & 1) * 8192;
#pragma unroll
      for (int c = 0; c < 4; c++) {
        const int row = w * 16 + c * 4 + t;
        const int ch = sl ^ (row & 7);
        gload16(Kg + (size_t)((kb + 1) * 64 + row) * DM + ch * 8, kn + w * 2048 + c * 512);
      }
#pragma unroll
      for (int c = 0; c < 4; c++) {
        const int row = w * 32 + c * 8 + t8;
        const int ch = sl8 ^ (row & 7);
        gload16(Vg + (size_t)row * SEQ + (kb + 1) * 64 + ch * 8, vn + w * 2048 + c * 512);
      }
    }
#pragma unroll
    for (int cb = 0; cb < 4; ++cb) {
      f32x4 s = {0.f, 0.f, 0.f, 0.f};
      const int key = cb * 16 + sl;
#pragma unroll
      for (int g = 0; g < 4; ++g) {
        const int ch = (g * 4 + t) ^ (key & 7);
        f16x8 kf = *(const f16x8*)&kc[key * 128 + ch * 8];
        s = __builtin_amdgcn_mfma_f32_16x16x32_f16(kf, qf[g], s, 0, 0, 0);
      }
      f32x4 p4;
      f16x4 ph;
#pragma unroll
      for (int j = 0; j < 4; j++) {
        const float p = __builtin_amdgcn_exp2f(s[j]) * inv;
        p4[j] = p;
        ph[j] = (f16)p;
      }
      __builtin_nontemporal_store(p4, (f32x4*)(Prow + kb * 64 + cb * 16 + t * 4));
      const int chs = (cb * 2 + (t >> 1)) ^ (qrow & 7);
      *(f16x4*)&lP[qrow * 64 + chs * 8 + (t & 1) * 4] = ph;
    }
    // lP rows are wave-private: ds ordering via lgkmcnt, no barrier needed
    f16x8 pf[2];
#pragma unroll
    for (int ks = 0; ks < 2; ++ks) {
      const int ch = (ks * 4 + t) ^ (qrow & 7);
      pf[ks] = *(const f16x8*)&lP[qrow * 64 + ch * 8];
    }
    __builtin_amdgcn_s_setprio(1);
#pragma unroll
    for (int cb = 0; cb < 8; ++cb) {
      const int d = cb * 16 + sl;
#pragma unroll
      for (int ks = 0; ks < 2; ++ks) {
        const int ch = (ks * 4 + t) ^ (d & 7);
        f16x8 vf = *(const f16x8*)&vc[d * 64 + ch * 8];
        oacc[cb] = __builtin_amdgcn_mfma_f32_16x16x32_f16(pf[ks], vf, oacc[cb], 0, 0, 0);
      }
    }
    __builtin_amdgcn_s_setprio(0);
    __syncthreads();
  }

  // O epilogue: [b,h,q,d] -> merged [n][2048] f16 for the final GEMM
#pragma unroll
  for (int cb = 0; cb < 8; ++cb) {
    const int d = cb * 16 + sl;
#pragma unroll
    for (int j = 0; j < 4; j++) {
      const int lrow = w * 16 + t * 4 + j;
      Oout[((size_t)(b * SEQ + q0 + lrow)) * DM + h * HD + d] = (f16)oacc[cb][j];
    }
  }
}

extern "C" void kernel_launch(void* const* d_in, const int* in_sizes, int n_in,
                              void* d_out, int out_size, void* d_ws, size_t ws_size,
                              hipStream_t stream) {
  const float* hs = (const float*)d_in[0];
  const float* Wq = (const float*)d_in[1];
  const float* bq = (const float*)d_in[2];
  const float* Wk = (const float*)d_in[3];
  const float* Wv = (const float*)d_in[4];
  const float* bv = (const float*)d_in[5];
  const float* Wo = (const float*)d_in[6];
  const float* bo = (const float*)d_in[7];
  float* out = (float*)d_out;
  float* Pout = out + (size_t)NT * DM;  // attn_weights region (134M f32)

  // d_ws: 4 x 16 MiB f16 buffers = 64 MiB
  f16* q16 = (f16*)d_ws;
  f16* k16 = q16 + (size_t)NT * DM;
  f16* vt16 = k16 + (size_t)NT * DM;
  f16* ao16 = vt16 + (size_t)NT * DM;
  // hs16 + Wqkv f16 scratch lives inside the P output region (fully
  // overwritten by attn later); Wo16 reuses q16 slot after attn is done.
  f16* hs16 = (f16*)Pout;
  f16* wqkv16 = hs16 + (size_t)NT * DM;  // [6144][2048] f16
  f16* wo16 = q16;

  cvt_f32_f16<<<2048, 256, 0, stream>>>(hs, hs16, NT * DM / 4);
  cvt3_f32_f16<<<2048, 256, 0, stream>>>(Wq, Wk, Wv, wqkv16);

  gemm8<3><<<dim3(6144 / 256, NT / 128), 512, 0, stream>>>(
      hs16, wqkv16, bq, bv, nullptr, q16, k16, vt16);

  attn<<<dim3(SEQ / 64, NBH), 256, 0, stream>>>(q16, k16, vt16, Pout, ao16);

  cvt_f32_f16<<<1024, 256, 0, stream>>>(Wo, wo16, DM * DM / 4);
  gemm8<0><<<dim3(DM / 256, NT / 128), 512, 0, stream>>>(
      ao16, wo16, bo, nullptr, out, nullptr, nullptr, nullptr);
}

// Round 7
// 379.863 us; speedup vs baseline: 1.2719x; 1.0225x over previous
//
#include <hip/hip_runtime.h>

typedef _Float16 f16;
typedef _Float16 f16x4 __attribute__((ext_vector_type(4)));
typedef _Float16 f16x8 __attribute__((ext_vector_type(8)));
typedef float f32x4 __attribute__((ext_vector_type(4)));

#define DM 2048
#define NT 4096
#define SEQ 2048
#define HD 128
#define NBH 32
// 1/sqrt(128) * log2(e): scores come out in log2 domain -> exp2 is one v_exp_f32
#define QSCALE (0.08838834764831845f * 1.4426950408889634f)

__device__ __forceinline__ void gload16(const f16* g, f16* l) {
  __builtin_amdgcn_global_load_lds(
      (const __attribute__((address_space(1))) void*)g,
      (__attribute__((address_space(3))) void*)l, 16, 0, 0);
}

#define LGKM0                                        \
  asm volatile("s_waitcnt lgkmcnt(0)" ::: "memory"); \
  __builtin_amdgcn_sched_barrier(0)
#define VMC6                                       \
  asm volatile("s_waitcnt vmcnt(6)" ::: "memory"); \
  __builtin_amdgcn_sched_barrier(0)
#define VMC4                                       \
  asm volatile("s_waitcnt vmcnt(4)" ::: "memory"); \
  __builtin_amdgcn_sched_barrier(0)
#define VMC0                                       \
  asm volatile("s_waitcnt vmcnt(0)" ::: "memory"); \
  __builtin_amdgcn_sched_barrier(0)

__global__ __launch_bounds__(256) void cvt_f32_f16(const float* __restrict__ src,
                                                   f16* __restrict__ dst, int n4) {
  int i = blockIdx.x * 256 + threadIdx.x;
  int st = gridDim.x * 256;
  for (; i < n4; i += st) {
    float4 v = ((const float4*)src)[i];
    f16x4 h = {(f16)v.x, (f16)v.y, (f16)v.z, (f16)v.w};
    ((f16x4*)dst)[i] = h;
  }
}

// merged convert: hs (2*2^20 f32x4) -> hsd, Wq/Wk/Wv (each 2^20) -> wd concat
__global__ __launch_bounds__(256) void cvt4_f32_f16(const float* __restrict__ hs,
                                                    const float* __restrict__ s0,
                                                    const float* __restrict__ s1,
                                                    const float* __restrict__ s2,
                                                    f16* __restrict__ hsd,
                                                    f16* __restrict__ wd) {
  int i = blockIdx.x * 256 + threadIdx.x;
  int st = gridDim.x * 256;
  for (; i < 5 * 1048576; i += st) {
    float4 v;
    f16x4 h;
    if (i < 2 * 1048576) {
      v = ((const float4*)hs)[i];
      h[0] = (f16)v.x; h[1] = (f16)v.y; h[2] = (f16)v.z; h[3] = (f16)v.w;
      ((f16x4*)hsd)[i] = h;
    } else {
      const int j = i - 2 * 1048576;
      const int r = j >> 20, jj = j & 1048575;
      const float* s = (r == 0) ? s0 : ((r == 1) ? s1 : s2);
      v = ((const float4*)s)[jj];
      h[0] = (f16)v.x; h[1] = (f16)v.y; h[2] = (f16)v.z; h[3] = (f16)v.w;
      ((f16x4*)wd)[j] = h;
    }
  }
}

// ============================================================================
// 8-phase-style GEMM: C = A(4096x2048) * B^T, B row-major [N][2048].
// Tile BM=128 x BN=256, BK=64, 8 waves (2M x 4N), wave tile 64x64.
// Triple-buffered LDS (144 KiB), staging issued 2 K-tiles ahead, counted
// vmcnt(6) at tile boundaries (T3+T4), XOR chunk-swizzle on LDS rows (T2),
// setprio around MFMA clusters (T5). 4 phases per K-tile.
// ============================================================================
template <int MODE>
__global__ __launch_bounds__(512, 2) void gemm8(const f16* __restrict__ A,
                                                const f16* __restrict__ Bm,
                                                const float* __restrict__ bias1,
                                                const float* __restrict__ bias2,
                                                float* __restrict__ outF,
                                                f16* __restrict__ outQ,
                                                f16* __restrict__ outK,
                                                f16* __restrict__ outV) {
  __shared__ __align__(16) f16 smem[73728];  // 144 KiB -> 1 block/CU, 8 waves
  const int tid = threadIdx.x;
  const int w = tid >> 6, l = tid & 63;
  const int wr = w >> 2, wc = w & 3;  // 2M x 4N wave grid
  const int sl = l & 15, t4 = l >> 4;

  const int nbx = gridDim.x;
  const int flat = blockIdx.y * nbx + blockIdx.x;
  const int chunk = (nbx * gridDim.y) >> 3;
  const int swz = (flat & 7) * chunk + (flat >> 3);
  const int row0 = (swz / nbx) * 128, col0 = (swz % nbx) * 256;

  f32x4 acc[4][4] = {};

  const int sr8 = l >> 3;
  const int sch = (l & 7) ^ (sr8 & 7);
  const f16* gA0 = A + (size_t)(row0 + w * 8 + sr8) * DM + sch * 8;
  const f16* gB0 = Bm + (size_t)(col0 + w * 8 + sr8) * DM + sch * 8;

#define SA(tb, kt, r) \
  gload16(gA0 + (size_t)(r) * 64 * DM + (kt) * 64, smem + (tb) * 8192 + (r) * 4096 + w * 512)
#define SB(tb, kt, r)                               \
  gload16(gB0 + (size_t)(r) * 64 * DM + (kt) * 64, \
          smem + 24576 + (tb) * 16384 + (r) * 4096 + w * 512)
#define MF(mi, ni, av, bv) \
  acc[mi][ni] = __builtin_amdgcn_mfma_f32_16x16x32_f16(av, bv, acc[mi][ni], 0, 0, 0)

  const int sx = sl & 7;
  const int sk0 = (t4 ^ sx) * 8;
  const int sk1 = ((4 + t4) ^ sx) * 8;
  const int arow = (wr * 64 + sl) * 64;
  const int brow = (wc * 64 + sl) * 64;

  SA(0, 0, 0); SA(0, 0, 1);
  SB(0, 0, 0); SB(0, 0, 1); SB(0, 0, 2); SB(0, 0, 3);
  SA(1, 1, 0); SA(1, 1, 1);
  SB(1, 1, 0); SB(1, 1, 1); SB(1, 1, 2); SB(1, 1, 3);
  VMC6;
  __builtin_amdgcn_s_barrier();

  int cur = 0;
#pragma unroll 1
  for (int t = 0; t < 32; ++t) {
    const int nb = (cur == 0) ? 2 : cur - 1;
    const bool pf = (t + 2 < 32);
    const int ab = cur * 8192;
    const int bb = 24576 + cur * 16384;
    f16x8 b0, b1, b2, b3, a0, a1;

    b0 = *(const f16x8*)&smem[bb + brow + sk0];
    b1 = *(const f16x8*)&smem[bb + brow + 1024 + sk0];
    b2 = *(const f16x8*)&smem[bb + brow + 2048 + sk0];
    b3 = *(const f16x8*)&smem[bb + brow + 3072 + sk0];
    a0 = *(const f16x8*)&smem[ab + arow + sk0];
    a1 = *(const f16x8*)&smem[ab + arow + 1024 + sk0];
    if (pf) { SA(nb, t + 2, 0); SA(nb, t + 2, 1); }
    __builtin_amdgcn_s_barrier();
    LGKM0;
    __builtin_amdgcn_s_setprio(1);
    MF(0, 0, a0, b0); MF(0, 1, a0, b1); MF(0, 2, a0, b2); MF(0, 3, a0, b3);
    MF(1, 0, a1, b0); MF(1, 1, a1, b1); MF(1, 2, a1, b2); MF(1, 3, a1, b3);
    __builtin_amdgcn_s_setprio(0);
    __builtin_amdgcn_s_barrier();

    a0 = *(const f16x8*)&smem[ab + arow + 2048 + sk0];
    a1 = *(const f16x8*)&smem[ab + arow + 3072 + sk0];
    if (pf) { SB(nb, t + 2, 0); SB(nb, t + 2, 1); }
    __builtin_amdgcn_s_barrier();
    LGKM0;
    __builtin_amdgcn_s_setprio(1);
    MF(2, 0, a0, b0); MF(2, 1, a0, b1); MF(2, 2, a0, b2); MF(2, 3, a0, b3);
    MF(3, 0, a1, b0); MF(3, 1, a1, b1); MF(3, 2, a1, b2); MF(3, 3, a1, b3);
    __builtin_amdgcn_s_setprio(0);
    __builtin_amdgcn_s_barrier();

    b0 = *(const f16x8*)&smem[bb + brow + sk1];
    b1 = *(const f16x8*)&smem[bb + brow + 1024 + sk1];
    b2 = *(const f16x8*)&smem[bb + brow + 2048 + sk1];
    b3 = *(const f16x8*)&smem[bb + brow + 3072 + sk1];
    a0 = *(const f16x8*)&smem[ab + arow + sk1];
    a1 = *(const f16x8*)&smem[ab + arow + 1024 + sk1];
    if (pf) { SB(nb, t + 2, 2); SB(nb, t + 2, 3); }
    __builtin_amdgcn_s_barrier();
    LGKM0;
    __builtin_amdgcn_s_setprio(1);
    MF(0, 0, a0, b0); MF(0, 1, a0, b1); MF(0, 2, a0, b2); MF(0, 3, a0, b3);
    MF(1, 0, a1, b0); MF(1, 1, a1, b1); MF(1, 2, a1, b2); MF(1, 3, a1, b3);
    __builtin_amdgcn_s_setprio(0);
    __builtin_amdgcn_s_barrier();

    a0 = *(const f16x8*)&smem[ab + arow + 2048 + sk1];
    a1 = *(const f16x8*)&smem[ab + arow + 3072 + sk1];
    __builtin_amdgcn_s_barrier();
    LGKM0;
    __builtin_amdgcn_s_setprio(1);
    MF(2, 0, a0, b0); MF(2, 1, a0, b1); MF(2, 2, a0, b2); MF(2, 3, a0, b3);
    MF(3, 0, a1, b0); MF(3, 1, a1, b1); MF(3, 2, a1, b2); MF(3, 3, a1, b3);
    __builtin_amdgcn_s_setprio(0);
    if (t < 30) { VMC6; } else { VMC0; }
    __builtin_amdgcn_s_barrier();
    cur = (cur == 2) ? 0 : cur + 1;
  }
#undef SA
#undef SB
#undef MF

  const int rl0 = wr * 64 + t4 * 4;
  const int cl0 = wc * 64 + sl;
  if constexpr (MODE == 0) {
#pragma unroll
    for (int mi = 0; mi < 4; mi++) {
#pragma unroll
      for (int ni = 0; ni < 4; ni++) {
        const int col = col0 + cl0 + ni * 16;
        const float bi = bias1[col];
#pragma unroll
        for (int j = 0; j < 4; j++) {
          const int row = row0 + rl0 + mi * 16 + j;
          outF[(size_t)row * DM + col] = acc[mi][ni][j] + bi;
        }
      }
    }
  } else {
    const int region = col0 >> 11;
    const int c2 = col0 & 2047;
    __syncthreads();
    if (region == 2) {
#pragma unroll
      for (int mi = 0; mi < 4; mi++)
#pragma unroll
        for (int ni = 0; ni < 4; ni++) {
          const int cl = cl0 + ni * 16;
          const float bb2 = bias2[c2 + cl];
#pragma unroll
          for (int j = 0; j < 4; j++)
            smem[cl * 136 + rl0 + mi * 16 + j] = (f16)(acc[mi][ni][j] + bb2);
        }
      __syncthreads();
      const int b = row0 >> 11, s0 = row0 & 2047;
#pragma unroll
      for (int it = 0; it < 8; ++it) {
        const int ck = it * 512 + tid;
        const int ci = ck >> 4, cc = (ck & 15) * 8;
        const int dg = c2 + ci;
        *(f16x8*)&outV[((size_t)(b * 16 + (dg >> 7)) * HD + (dg & 127)) * SEQ + s0 + cc] =
            *(const f16x8*)&smem[ci * 136 + cc];
      }
    } else {
#pragma unroll
      for (int mi = 0; mi < 4; mi++)
#pragma unroll
        for (int ni = 0; ni < 4; ni++) {
          const int cl = cl0 + ni * 16;
          const int cg = c2 + cl;
          const float badd = (region == 0) ? bias1[cg] : 0.0f;
#pragma unroll
          for (int j = 0; j < 4; j++) {
            float v = acc[mi][ni][j] + badd;
            if (region == 0) v *= QSCALE;
            smem[(rl0 + mi * 16 + j) * 264 + cl] = (f16)v;
          }
        }
      __syncthreads();
      f16* const dst = (region == 0 ? outQ : outK) + (size_t)row0 * DM + c2;
#pragma unroll
      for (int it = 0; it < 8; ++it) {
        const int ck = it * 512 + tid;
        const int rr = ck >> 5, cc = (ck & 31) * 8;
        *(f16x8*)&dst[(size_t)rr * DM + cc] = *(const f16x8*)&smem[rr * 264 + cc];
      }
    }
  }
}

// Attention: one block = 64 q rows of one (b,h). Pass 1: 4-deep K ring,
// 2-ahead prefetch, counted vmcnt(4) + raw barrier (never drain mid-loop).
// Pass 2: K/V dbuf, prefetch issued BEFORE the P stores so the end-of-iter
// vmcnt(4) waits only the loads (stores drain in the next iter's shadow).
__global__ __launch_bounds__(256, 2) void attn(const f16* __restrict__ Q,
                                               const f16* __restrict__ Kt,
                                               const f16* __restrict__ Vt,
                                               float* __restrict__ Pout,
                                               f16* __restrict__ Oout) {
  __shared__ __align__(16) f16 smem[36864];  // 72 KiB -> 2 blocks/CU
  // pass 1: K ring bufs 0..3 @ (kb&3)*8192 (16 KB each)
  // pass 2: K @ (kb&1)*8192, V @ 16384+(kb&1)*8192, lP @ 32768
  f16* const lP = smem + 32768;

  const int tid = threadIdx.x, w = tid >> 6, l = tid & 63;
  const int t = l >> 4, sl = l & 15, t8 = l >> 3, sl8 = l & 7;

  // XCD swizzle: each XCD owns 4 whole (b,h) -> K/V L2-resident
  const int flat = blockIdx.y * gridDim.x + blockIdx.x;
  const int swz = (flat & 7) * 128 + (flat >> 3);
  const int bh = swz >> 5, q0 = (swz & 31) * 64;

  const int b = bh >> 4, h = bh & 15;
  const f16* Qg = Q + (size_t)(b * SEQ) * DM + h * HD;
  const f16* Kg = Kt + (size_t)(b * SEQ) * DM + h * HD;
  const f16* Vg = Vt + (size_t)bh * HD * SEQ;

  // ---- prologue: Q -> buf2, K0 -> buf0, K1 -> buf1
#pragma unroll
  for (int c = 0; c < 4; c++) {
    const int row = w * 16 + c * 4 + t;
    const int ch = sl ^ (row & 7);
    gload16(Qg + (size_t)(q0 + row) * DM + ch * 8, smem + 16384 + w * 2048 + c * 512);
    gload16(Kg + (size_t)row * DM + ch * 8, smem + w * 2048 + c * 512);
    gload16(Kg + (size_t)(64 + row) * DM + ch * 8, smem + 8192 + w * 2048 + c * 512);
  }
  __syncthreads();

  f16x8 qf[4];
  {
    const int row = w * 16 + sl;
#pragma unroll
    for (int g = 0; g < 4; g++) {
      const int ch = (g * 4 + t) ^ (row & 7);
      qf[g] = *(const f16x8*)&smem[16384 + row * 128 + ch * 8];
    }
  }
  // all waves done reading Q from buf2 before pass-1 prefetch reuses it
  LGKM0;
  __builtin_amdgcn_s_barrier();

  float lsum = 0.0f;

  // ---- pass 1: row sums of exp2(S'), 4-deep K ring, 2-ahead prefetch
  for (int kb = 0; kb < 32; ++kb) {
    f16* const kc = smem + (kb & 3) * 8192;
    if (kb + 2 < 32) {
      f16* const kn = smem + ((kb + 2) & 3) * 8192;
#pragma unroll
      for (int c = 0; c < 4; c++) {
        const int row = w * 16 + c * 4 + t;
        const int ch = sl ^ (row & 7);
        gload16(Kg + (size_t)((kb + 2) * 64 + row) * DM + ch * 8, kn + w * 2048 + c * 512);
      }
    }
#pragma unroll
    for (int cb = 0; cb < 4; ++cb) {
      f32x4 s = {0.f, 0.f, 0.f, 0.f};
      const int key = cb * 16 + sl;
#pragma unroll
      for (int g = 0; g < 4; ++g) {
        const int ch = (g * 4 + t) ^ (key & 7);
        f16x8 kf = *(const f16x8*)&kc[key * 128 + ch * 8];
        s = __builtin_amdgcn_mfma_f32_16x16x32_f16(kf, qf[g], s, 0, 0, 0);
      }
#pragma unroll
      for (int j = 0; j < 4; j++) lsum += __builtin_amdgcn_exp2f(s[j]);
    }
    if (kb < 31) {
      if (kb + 2 < 32) { VMC4; } else { VMC0; }  // next tile's loads complete
      __builtin_amdgcn_s_barrier();
    }
  }
  lsum += __shfl_xor(lsum, 16);
  lsum += __shfl_xor(lsum, 32);
  const float inv = 1.0f / lsum;  // full row sum for qrow = w*16 + (l&15)

  // ---- pass 2 prologue: stage K0 + V0 (buf0 reads long since done)
  {
#pragma unroll
    for (int c = 0; c < 4; c++) {
      const int row = w * 16 + c * 4 + t;
      const int ch = sl ^ (row & 7);
      gload16(Kg + (size_t)row * DM + ch * 8, smem + w * 2048 + c * 512);
    }
#pragma unroll
    for (int c = 0; c < 4; c++) {
      const int row = w * 32 + c * 8 + t8;
      const int ch = sl8 ^ (row & 7);
      gload16(Vg + (size_t)row * SEQ + ch * 8, smem + 16384 + w * 2048 + c * 512);
    }
  }
  __syncthreads();

  f32x4 oacc[8] = {};
  const int qrow = w * 16 + sl;
  float* const Prow = Pout + ((size_t)bh * SEQ + q0 + qrow) * SEQ;

  // ---- pass 2: recompute S, write normalized P (nt f32x4), accumulate PV
  for (int kb = 0; kb < 32; ++kb) {
    f16* const kc = smem + (kb & 1) * 8192;
    f16* const vc = smem + 16384 + (kb & 1) * 8192;
    if (kb < 31) {  // loads issued FIRST (older than the stores below)
      f16* const kn = smem + ((kb + 1) & 1) * 8192;
      f16* const vn = smem + 16384 + ((kb + 1) & 1) * 8192;
#pragma unroll
      for (int c = 0; c < 4; c++) {
        const int row = w * 16 + c * 4 + t;
        const int ch = sl ^ (row & 7);
        gload16(Kg + (size_t)((kb + 1) * 64 + row) * DM + ch * 8, kn + w * 2048 + c * 512);
      }
#pragma unroll
      for (int c = 0; c < 4; c++) {
        const int row = w * 32 + c * 8 + t8;
        const int ch = sl8 ^ (row & 7);
        gload16(Vg + (size_t)row * SEQ + (kb + 1) * 64 + ch * 8, vn + w * 2048 + c * 512);
      }
    }
#pragma unroll
    for (int cb = 0; cb < 4; ++cb) {
      f32x4 s = {0.f, 0.f, 0.f, 0.f};
      const int key = cb * 16 + sl;
#pragma unroll
      for (int g = 0; g < 4; ++g) {
        const int ch = (g * 4 + t) ^ (key & 7);
        f16x8 kf = *(const f16x8*)&kc[key * 128 + ch * 8];
        s = __builtin_amdgcn_mfma_f32_16x16x32_f16(kf, qf[g], s, 0, 0, 0);
      }
      f32x4 p4;
      f16x4 ph;
#pragma unroll
      for (int j = 0; j < 4; j++) {
        const float p = __builtin_amdgcn_exp2f(s[j]) * inv;
        p4[j] = p;
        ph[j] = (f16)p;
      }
      __builtin_nontemporal_store(p4, (f32x4*)(Prow + kb * 64 + cb * 16 + t * 4));
      const int chs = (cb * 2 + (t >> 1)) ^ (qrow & 7);
      *(f16x4*)&lP[qrow * 64 + chs * 8 + (t & 1) * 4] = ph;
    }
    // lP rows are wave-private: ds ordering via lgkmcnt, no barrier needed
    f16x8 pf[2];
#pragma unroll
    for (int ks = 0; ks < 2; ++ks) {
      const int ch = (ks * 4 + t) ^ (qrow & 7);
      pf[ks] = *(const f16x8*)&lP[qrow * 64 + ch * 8];
    }
    __builtin_amdgcn_s_setprio(1);
#pragma unroll
    for (int cb = 0; cb < 8; ++cb) {
      const int d = cb * 16 + sl;
#pragma unroll
      for (int ks = 0; ks < 2; ++ks) {
        const int ch = (ks * 4 + t) ^ (d & 7);
        f16x8 vf = *(const f16x8*)&vc[d * 64 + ch * 8];
        oacc[cb] = __builtin_amdgcn_mfma_f32_16x16x32_f16(pf[ks], vf, oacc[cb], 0, 0, 0);
      }
    }
    __builtin_amdgcn_s_setprio(0);
    if (kb < 31) {
      VMC4;  // 8 loads (older) retired; <=4 P-stores may still be in flight
      __builtin_amdgcn_s_barrier();
    }
  }

  // O epilogue: [b,h,q,d] -> merged [n][2048] f16 for the final GEMM
#pragma unroll
  for (int cb = 0; cb < 8; ++cb) {
    const int d = cb * 16 + sl;
#pragma unroll
    for (int j = 0; j < 4; j++) {
      const int lrow = w * 16 + t * 4 + j;
      Oout[((size_t)(b * SEQ + q0 + lrow)) * DM + h * HD + d] = (f16)oacc[cb][j];
    }
  }
}

extern "C" void kernel_launch(void* const* d_in, const int* in_sizes, int n_in,
                              void* d_out, int out_size, void* d_ws, size_t ws_size,
                              hipStream_t stream) {
  const float* hs = (const float*)d_in[0];
  const float* Wq = (const float*)d_in[1];
  const float* bq = (const float*)d_in[2];
  const float* Wk = (const float*)d_in[3];
  const float* Wv = (const float*)d_in[4];
  const float* bv = (const float*)d_in[5];
  const float* Wo = (const float*)d_in[6];
  const float* bo = (const float*)d_in[7];
  float* out = (float*)d_out;
  float* Pout = out + (size_t)NT * DM;  // attn_weights region (134M f32)

  // d_ws: 4 x 16 MiB f16 buffers = 64 MiB
  f16* q16 = (f16*)d_ws;
  f16* k16 = q16 + (size_t)NT * DM;
  f16* vt16 = k16 + (size_t)NT * DM;
  f16* ao16 = vt16 + (size_t)NT * DM;
  // hs16 + Wqkv f16 scratch lives inside the P output region (fully
  // overwritten by attn later); Wo16 reuses q16 slot after attn is done.
  f16* hs16 = (f16*)Pout;
  f16* wqkv16 = hs16 + (size_t)NT * DM;  // [6144][2048] f16
  f16* wo16 = q16;

  cvt4_f32_f16<<<2048, 256, 0, stream>>>(hs, Wq, Wk, Wv, hs16, wqkv16);

  gemm8<3><<<dim3(6144 / 256, NT / 128), 512, 0, stream>>>(
      hs16, wqkv16, bq, bv, nullptr, q16, k16, vt16);

  attn<<<dim3(SEQ / 64, NBH), 256, 0, stream>>>(q16, k16, vt16, Pout, ao16);

  cvt_f32_f16<<<1024, 256, 0, stream>>>(Wo, wo16, DM * DM / 4);
  gemm8<0><<<dim3(DM / 256, NT / 128), 512, 0, stream>>>(
      ao16, wo16, bo, nullptr, out, nullptr, nullptr, nullptr);
}